// Round 27
// baseline (189.024 us; speedup 1.0000x reference)
//
#include <hip/hip_runtime.h>
#include <hip/hip_bf16.h>
#include <hip/hip_cooperative_groups.h>
#include <stdint.h>

namespace cg = cooperative_groups;

#define NN 8192
#define CC 256
#define DD 16                              // poly terms (degree 15)
#define NCH 512                            // moment j-chunks
#define JCH 16                             // j per chunk
#define FITHALF 5.0                        // Chebyshev fit on [-5,5]; |s_i+s_j+c0|<=~3.2

typedef float f32x4 __attribute__((ext_vector_type(4)));
typedef float f32x2 __attribute__((ext_vector_type(2)));

// ---- workspace layout (float offsets). Total ~17.2 MB. ----
#define OFF_WT  0                          // 256*256 transposed w_reduce
#define OFF_R   (OFF_WT + CC*CC)           // N*C fp32 r
#define OFF_S   (OFF_R + NN*CC)            // N fp32 s
#define OFF_C0  (OFF_S + NN)               // [0]=c0
#define OFF_SP  (OFF_C0 + 16)              // 4*N fp32 s partials (per colblk)
#define OFF_D   (OFF_SP + 4*NN)            // 16x16 d[k][m] = c_k * C(k,m)
#define OFF_MU  (OFF_D + 256)              // 16 mu_p = sum_j s_j^p
#define OFF_M   (OFF_MU + 16)              // 16x256 M_p[c] = sum_j s_j^p r_j[c]
#define OFF_PM  (OFF_M + DD*CC)            // NCH x 16x256 partial M (8.4 MB)
#define OFF_PMU (OFF_PM + NCH*DD*CC)       // NCH x 16 partial mu

// -- kernel 1: 65 blocks. 0-63: tiled transpose Wr (+c0 in blk 0); 64: fit. --
__global__ __launch_bounds__(256) void k_prep(const float* __restrict__ w,
                                              const float* __restrict__ br,
                                              const float* __restrict__ wcv,
                                              const float* __restrict__ bc,
                                              float* __restrict__ ws) {
  __shared__ float t[32][33];
  __shared__ double fd[32], cnod[32], ac[16], alpha[16][16], cmon[16];
  int bi = blockIdx.x;
  if (bi < 64) {                           // ---- transpose path ----
    int tr = bi >> 3, tc = bi & 7;
    int tx = threadIdx.x & 31, ty = threadIdx.x >> 5;
    #pragma unroll
    for (int p = 0; p < 4; p++) {
      int row = ty + p * 8;
      t[row][tx] = w[(tr * 32 + row) * CC + tc * 32 + tx];
    }
    __syncthreads();
    #pragma unroll
    for (int p = 0; p < 4; p++) {
      int row = ty + p * 8;
      ws[OFF_WT + (tc * 32 + row) * CC + tr * 32 + tx] = t[tx][row];
    }
    if (bi == 0 && threadIdx.x < 64) {
      int lane = threadIdx.x;
      f32x4 b4 = *(const f32x4*)&br[lane * 4];
      f32x4 w4 = *(const f32x4*)&wcv[lane * 4];
      float d = b4[0]*w4[0] + b4[1]*w4[1] + b4[2]*w4[2] + b4[3]*w4[3];
      #pragma unroll
      for (int m = 32; m >= 1; m >>= 1) d += __shfl_xor(d, m, 64);
      if (lane == 0) ws[OFF_C0] = d + bc[0];
    }
  } else {                                 // ---- Chebyshev fit path ----
    int tt = threadIdx.x;
    if (tt < 32) {
      double th = (3.14159265358979323846 * (tt + 0.5)) / 32.0;
      double c = cos(th);
      cnod[tt] = c;
      fd[tt] = 1.0 / (1.0 + exp(-FITHALF * c));
    }
    __syncthreads();
    if (tt < 16) {                         // DCT -> Chebyshev coeffs
      double sum = 0.0;
      for (int n = 0; n < 32; n++) {
        double t0 = 1.0, t1 = cnod[n], tk = t1;
        for (int k = 2; k <= tt; k++) { tk = 2.0 * cnod[n] * t1 - t0; t0 = t1; t1 = tk; }
        if (tt == 0) tk = 1.0;
        sum += fd[n] * tk;
      }
      ac[tt] = ((tt == 0) ? 1.0 : 2.0) / 32.0 * sum;
    }
    __syncthreads();
    if (tt == 0) {                         // Cheb->monomial basis (in u=y/H)
      for (int k = 0; k < 16; k++) for (int m = 0; m < 16; m++) alpha[k][m] = 0.0;
      alpha[0][0] = 1.0; alpha[1][1] = 1.0;
      for (int k = 2; k < 16; k++)
        for (int m = 0; m < 16; m++) {
          double v = -alpha[k-2][m];
          if (m > 0) v += 2.0 * alpha[k-1][m-1];
          alpha[k][m] = v;
        }
    }
    __syncthreads();
    if (tt < 16) {                         // cmon[m], parallel over m
      double pm = 0.0;
      for (int k = 0; k < 16; k++) pm += ac[k] * alpha[k][tt];
      double p5 = 1.0;
      for (int i = 0; i < tt; i++) p5 *= FITHALF;
      cmon[tt] = pm / p5;
    }
    __syncthreads();
    if (tt == 0) {                         // Pascal binomials
      for (int k = 0; k < 16; k++) for (int m = 0; m < 16; m++) alpha[k][m] = 0.0;
      alpha[0][0] = 1.0;
      for (int k = 1; k < 16; k++)
        for (int m = 0; m <= k; m++)
          alpha[k][m] = ((m > 0) ? alpha[k-1][m-1] : 0.0) + ((m < k) ? alpha[k-1][m] : 0.0);
    }
    __syncthreads();
    {                                      // d[k][m] = c_k * C(k,m), 256 threads
      int k = tt >> 4, m = tt & 15;
      ws[OFF_D + tt] = (float)((m <= k) ? cmon[k] * alpha[k][m] : 0.0);
    }
  }
}

// ------- kernel 2: r = x @ Wr^T (fp32) + s partials (proven R21 core) -------
__global__ __launch_bounds__(256) void k_r(const float* __restrict__ x,
                                           const float* __restrict__ wcv,
                                           float* __restrict__ ws) {
  __shared__ float xs[64][260];
  int bi = blockIdx.x;
  int rowblk = bi >> 2, colblk = bi & 3;
  int tid = threadIdx.x;
  int i0 = rowblk * 64;
  for (int t = tid; t < 64 * 64; t += 256) {
    int rr = t >> 6, c4 = t & 63;
    *(f32x4*)&xs[rr][c4 * 4] = *(const f32x4*)&x[(i0 + rr) * CC + c4 * 4];
  }
  __syncthreads();
  int tx = tid & 15, ty = tid >> 4;
  int cbase = colblk * 64 + tx * 4;
  int r0 = ty * 4;
  float acc[4][4] = {};
  const float* wt = ws + OFF_WT;
  for (int k = 0; k < CC; k += 2) {
    f32x4 wv0 = *(const f32x4*)&wt[k * CC + cbase];
    f32x4 wv1 = *(const f32x4*)&wt[(k + 1) * CC + cbase];
    f32x2 xv[4];
    #pragma unroll
    for (int rr = 0; rr < 4; rr++) xv[rr] = *(const f32x2*)&xs[r0 + rr][k];
    #pragma unroll
    for (int rr = 0; rr < 4; rr++)
      #pragma unroll
      for (int cc = 0; cc < 4; cc++)
        acc[rr][cc] = fmaf(xv[rr][1], wv1[cc], fmaf(xv[rr][0], wv0[cc], acc[rr][cc]));
  }
  #pragma unroll
  for (int rr = 0; rr < 4; rr++) {
    f32x4 o = {acc[rr][0], acc[rr][1], acc[rr][2], acc[rr][3]};
    *(f32x4*)&ws[OFF_R + (size_t)(i0 + r0 + rr) * CC + cbase] = o;
  }
  // s partials: this block's 64-col contribution, shuffle-reduced over tx
  f32x4 wc4 = *(const f32x4*)&wcv[cbase];
  float sd[4];
  #pragma unroll
  for (int rr = 0; rr < 4; rr++) {
    sd[rr] = acc[rr][0]*wc4[0] + acc[rr][1]*wc4[1] + acc[rr][2]*wc4[2] + acc[rr][3]*wc4[3];
    #pragma unroll
    for (int m = 1; m < 16; m <<= 1) sd[rr] += __shfl_xor(sd[rr], m, 64);
  }
  if (tx == 0) {
    int j0r = i0 + r0;
    #pragma unroll
    for (int rr = 0; rr < 4; rr++)
      ws[OFF_SP + colblk * NN + j0r + rr] = sd[rr];
  }
}

// ---- kernel 3 (cooperative, 512 blocks): moments -> reduce -> output -------
__global__ __launch_bounds__(256) void k_coop(const float* __restrict__ br,
                                              float* __restrict__ ws,
                                              float* __restrict__ out) {
  cg::grid_group grid = cg::this_grid();
  __shared__ float lds[DD * CC];           // 16 KB, reused across phases
  __shared__ float dt[256], mul[DD], brl[CC];
  __shared__ float red[16][17];
  int b = blockIdx.x;
  int tid = threadIdx.x;

  // ---- P1: finalize s + partial moments (R26 k_mom verbatim) ----
  {
    int j0 = b * JCH;
    if (tid < JCH) {
      int j = j0 + tid;
      float s = ws[OFF_SP + j] + ws[OFF_SP + NN + j]
              + ws[OFF_SP + 2 * NN + j] + ws[OFF_SP + 3 * NN + j];
      lds[tid] = s;
      ws[OFF_S + j] = s;
    }
    __syncthreads();
    float acc[DD];
    #pragma unroll
    for (int p = 0; p < DD; p++) acc[p] = 0.f;
    const float* Rp = ws + OFF_R;
    #pragma unroll
    for (int jj = 0; jj < JCH; jj++) {
      float rv = Rp[(size_t)(j0 + jj) * CC + tid];
      float sj = lds[jj];
      float pw = 1.f;
      #pragma unroll
      for (int p = 0; p < DD; p++) { acc[p] = fmaf(pw, rv, acc[p]); pw *= sj; }
    }
    #pragma unroll
    for (int p = 0; p < DD; p++)
      ws[OFF_PM + ((size_t)b * DD + p) * CC + tid] = acc[p];
    if (tid < DD) {
      float m = 0.f;
      for (int jj = 0; jj < JCH; jj++) {
        float sj = lds[jj], pw = 1.f;
        for (int p = 0; p < tid; p++) pw *= sj;
        m += pw;
      }
      ws[OFF_PMU + b * DD + tid] = m;
    }
  }
  grid.sync();

  // ---- P2: reduce partials -> M, mu (R26 k_mred layout, blocks 0-256) ----
  {
    int posL = tid & 15, grp = tid >> 4;
    if (b < 256) {
      int pos = b * 16 + posL;
      int b0 = grp * 32;
      float s0 = 0.f, s1 = 0.f, s2 = 0.f, s3 = 0.f;
      #pragma unroll
      for (int k = 0; k < 32; k += 4) {
        s0 += ws[OFF_PM + (size_t)(b0 + k + 0) * (DD * CC) + pos];
        s1 += ws[OFF_PM + (size_t)(b0 + k + 1) * (DD * CC) + pos];
        s2 += ws[OFF_PM + (size_t)(b0 + k + 2) * (DD * CC) + pos];
        s3 += ws[OFF_PM + (size_t)(b0 + k + 3) * (DD * CC) + pos];
      }
      red[grp][posL] = (s0 + s1) + (s2 + s3);
      __syncthreads();
      if (grp == 0) {
        float m = 0.f;
        #pragma unroll
        for (int k = 0; k < 16; k++) m += red[k][posL];
        ws[OFF_M + pos] = m;
      }
    } else if (b == 256) {
      int b0 = grp * 32;
      float s = 0.f;
      #pragma unroll
      for (int k = 0; k < 32; k++)
        s += ws[OFF_PMU + (b0 + k) * DD + posL];
      red[grp][posL] = s;
      __syncthreads();
      if (grp == 0) {
        float m = 0.f;
        #pragma unroll
        for (int k = 0; k < 16; k++) m += red[k][posL];
        ws[OFF_MU + posL] = m;
      }
    }
  }
  grid.sync();

  // ---- P3: out = (r+b)*m_i + (Z@r)_i/N. 512 blocks x 16 rows. ----
  {
    #pragma unroll
    for (int q = 0; q < DD; q++) lds[q * CC + tid] = ws[OFF_M + q * CC + tid];
    dt[tid] = ws[OFF_D + tid];
    brl[tid] = br[tid];
    if (tid < DD) mul[tid] = ws[OFF_MU + tid];
    __syncthreads();
    int i = b * 16 + (tid >> 4);
    int l16 = tid & 15;
    float a = ws[OFF_S + i] + ws[OFF_C0];
    float apow[DD];
    apow[0] = 1.f;
    #pragma unroll
    for (int p = 1; p < DD; p++) apow[p] = apow[p - 1] * a;
    float Q[DD];
    #pragma unroll
    for (int m = 0; m < DD; m++) {
      float q = 0.f;
      #pragma unroll
      for (int t = 0; t + m < DD; t++)
        q = fmaf(dt[(m + t) * 16 + m], apow[t], q);
      Q[m] = q;
    }
    float mi = 0.f;
    #pragma unroll
    for (int m = 0; m < DD; m++) mi = fmaf(Q[m], mul[m], mi);
    mi *= (1.0f / NN);
    #pragma unroll
    for (int t4 = 0; t4 < 4; t4++) {
      int c0 = l16 * 16 + t4 * 4;
      f32x4 rv = *(const f32x4*)&ws[OFF_R + (size_t)i * CC + c0];
      f32x4 o;
      #pragma unroll
      for (int e = 0; e < 4; e++) {
        int c = c0 + e;
        float v = 0.f;
        #pragma unroll
        for (int m = 0; m < DD; m++) v = fmaf(Q[m], lds[m * CC + c], v);
        o[e] = (rv[e] + brl[c]) * mi + v * (1.0f / NN);
      }
      *(f32x4*)&out[(size_t)i * CC + c0] = o;
    }
  }
}

extern "C" void kernel_launch(void* const* d_in, const int* in_sizes, int n_in,
                              void* d_out, int out_size, void* d_ws, size_t ws_size,
                              hipStream_t stream) {
  const float* x  = (const float*)d_in[0];
  const float* w  = (const float*)d_in[1];
  const float* br = (const float*)d_in[2];
  const float* wc = (const float*)d_in[3];
  const float* bc = (const float*)d_in[4];
  float* ws = (float*)d_ws;
  float* out = (float*)d_out;
  (void)in_sizes; (void)n_in; (void)out_size; (void)ws_size;

  k_prep<<<65, 256, 0, stream>>>(w, br, wc, bc, ws);
  k_r<<<512, 256, 0, stream>>>(x, wc, ws);
  void* args[] = {(void*)&br, (void*)&ws, (void*)&out};
  hipLaunchCooperativeKernel((void*)k_coop, dim3(512), dim3(256), args, 0, stream);
}

// Round 29
// 92.291 us; speedup vs baseline: 2.0481x; 2.0481x over previous
//
#include <hip/hip_runtime.h>
#include <hip/hip_bf16.h>
#include <stdint.h>

#define NN 8192
#define CC 256
#define DD 16                              // poly terms (degree 15)
#define NCH 512                            // moment j-chunks
#define JCH 16                             // j per chunk
#define FITHALF 5.0                        // Chebyshev fit on [-5,5]; |s_i+s_j+c0|<=~3.2

typedef float f32x4 __attribute__((ext_vector_type(4)));
typedef float f32x2 __attribute__((ext_vector_type(2)));

// ---- workspace layout (float offsets). Total ~17.2 MB. ----
#define OFF_R   0                          // N*C fp32 r
#define OFF_S   (OFF_R + NN*CC)            // N fp32 s
#define OFF_C0  (OFF_S + NN)               // [0]=c0
#define OFF_SP  (OFF_C0 + 16)              // 4*N fp32 s partials (per colblk)
#define OFF_D   (OFF_SP + 4*NN)            // 16x16 d[k][m] = c_k * C(k,m)
#define OFF_MU  (OFF_D + 256)              // 16 mu_p = sum_j s_j^p
#define OFF_M   (OFF_MU + 16)              // 16x256 M_p[c] = sum_j s_j^p r_j[c]
#define OFF_PM  (OFF_M + DD*CC)            // NCH x 16x256 partial M (8.4 MB)
#define OFF_PMU (OFF_PM + NCH*DD*CC)       // NCH x 16 partial mu

// -- kernel 1 (1 block): Chebyshev fit of sigmoid + c0 -----------------------
__global__ __launch_bounds__(256) void k_fit(const float* __restrict__ br,
                                             const float* __restrict__ wcv,
                                             const float* __restrict__ bc,
                                             float* __restrict__ ws) {
  __shared__ double fd[32], cnod[32], ac[16], alpha[16][16], cmon[16];
  int tt = threadIdx.x;
  if (tt < 64) {                           // c0 (wave 0)
    int lane = tt;
    f32x4 b4 = *(const f32x4*)&br[lane * 4];
    f32x4 w4 = *(const f32x4*)&wcv[lane * 4];
    float d = b4[0]*w4[0] + b4[1]*w4[1] + b4[2]*w4[2] + b4[3]*w4[3];
    #pragma unroll
    for (int m = 32; m >= 1; m >>= 1) d += __shfl_xor(d, m, 64);
    if (lane == 0) ws[OFF_C0] = d + bc[0];
  }
  if (tt >= 64 && tt < 96) {               // nodes (wave 1)
    int n = tt - 64;
    double th = (3.14159265358979323846 * (n + 0.5)) / 32.0;
    double c = cos(th);
    cnod[n] = c;
    fd[n] = 1.0 / (1.0 + exp(-FITHALF * c));
  }
  __syncthreads();
  if (tt < 16) {                           // DCT -> Chebyshev coeffs
    double sum = 0.0;
    for (int n = 0; n < 32; n++) {
      double t0 = 1.0, t1 = cnod[n], tk = t1;
      for (int k = 2; k <= tt; k++) { tk = 2.0 * cnod[n] * t1 - t0; t0 = t1; t1 = tk; }
      if (tt == 0) tk = 1.0;
      sum += fd[n] * tk;
    }
    ac[tt] = ((tt == 0) ? 1.0 : 2.0) / 32.0 * sum;
  }
  __syncthreads();
  if (tt == 0) {                           // Cheb->monomial basis (in u=y/H)
    for (int k = 0; k < 16; k++) for (int m = 0; m < 16; m++) alpha[k][m] = 0.0;
    alpha[0][0] = 1.0; alpha[1][1] = 1.0;
    for (int k = 2; k < 16; k++)
      for (int m = 0; m < 16; m++) {
        double v = -alpha[k-2][m];
        if (m > 0) v += 2.0 * alpha[k-1][m-1];
        alpha[k][m] = v;
      }
  }
  __syncthreads();
  if (tt < 16) {                           // cmon[m]
    double pm = 0.0;
    for (int k = 0; k < 16; k++) pm += ac[k] * alpha[k][tt];
    double p5 = 1.0;
    for (int i = 0; i < tt; i++) p5 *= FITHALF;
    cmon[tt] = pm / p5;
  }
  __syncthreads();
  if (tt == 0) {                           // Pascal binomials
    for (int k = 0; k < 16; k++) for (int m = 0; m < 16; m++) alpha[k][m] = 0.0;
    alpha[0][0] = 1.0;
    for (int k = 1; k < 16; k++)
      for (int m = 0; m <= k; m++)
        alpha[k][m] = ((m > 0) ? alpha[k-1][m-1] : 0.0) + ((m < k) ? alpha[k-1][m] : 0.0);
  }
  __syncthreads();
  {                                        // d[k][m] = c_k * C(k,m)
    int k = tt >> 4, m = tt & 15;
    ws[OFF_D + tt] = (float)((m <= k) ? cmon[k] * alpha[k][m] : 0.0);
  }
}

// -- kernel 2: r = x @ Wr^T + s partials; W transposed per-block in LDS ------
__global__ __launch_bounds__(256) void k_r(const float* __restrict__ x,
                                           const float* __restrict__ w,
                                           const float* __restrict__ wcv,
                                           float* __restrict__ ws) {
  __shared__ float xs[64][260];
  __shared__ float wtl[64][65];            // this colblk's W rows, transposed
  int bi = blockIdx.x;
  int rowblk = bi >> 2, colblk = bi & 3;
  int tid = threadIdx.x;
  int i0 = rowblk * 64;
  for (int t = tid; t < 64 * 64; t += 256) {
    int rr = t >> 6, c4 = t & 63;
    *(f32x4*)&xs[rr][c4 * 4] = *(const f32x4*)&x[(i0 + rr) * CC + c4 * 4];
  }
  __syncthreads();
  int tx = tid & 15, ty = tid >> 4;
  int cbase = colblk * 64 + tx * 4;
  int r0 = ty * 4;
  float acc[4][4] = {};
  // K-tiled: for each 64-k tile, transpose W[cbase..][k..] into LDS, then FMA.
  for (int k0 = 0; k0 < CC; k0 += 64) {
    __syncthreads();
    // wtl[kk][cc] = w[(colblk*64+cc)*CC + k0+kk]; 64 cols x 16 k-quads = 4 iters
    #pragma unroll
    for (int it = 0; it < 4; it++) {
      int cc = (tid >> 4) + it * 16, k4 = (tid & 15) * 4;
      f32x4 wv = *(const f32x4*)&w[(colblk * 64 + cc) * CC + k0 + k4];
      wtl[k4 + 0][cc] = wv[0];
      wtl[k4 + 1][cc] = wv[1];
      wtl[k4 + 2][cc] = wv[2];
      wtl[k4 + 3][cc] = wv[3];
    }
    __syncthreads();
    for (int kk = 0; kk < 64; kk += 2) {
      int k = k0 + kk;
      f32x4 wv0 = *(const f32x4*)&wtl[kk][tx * 4];
      f32x4 wv1 = *(const f32x4*)&wtl[kk + 1][tx * 4];
      f32x2 xv[4];
      #pragma unroll
      for (int rr = 0; rr < 4; rr++) xv[rr] = *(const f32x2*)&xs[r0 + rr][k];
      #pragma unroll
      for (int rr = 0; rr < 4; rr++)
        #pragma unroll
        for (int cc = 0; cc < 4; cc++)
          acc[rr][cc] = fmaf(xv[rr][1], wv1[cc], fmaf(xv[rr][0], wv0[cc], acc[rr][cc]));
    }
  }
  #pragma unroll
  for (int rr = 0; rr < 4; rr++) {
    f32x4 o = {acc[rr][0], acc[rr][1], acc[rr][2], acc[rr][3]};
    *(f32x4*)&ws[OFF_R + (size_t)(i0 + r0 + rr) * CC + cbase] = o;
  }
  // s partials: this block's 64-col contribution, shuffle-reduced over tx
  f32x4 wc4 = *(const f32x4*)&wcv[cbase];
  float sd[4];
  #pragma unroll
  for (int rr = 0; rr < 4; rr++) {
    sd[rr] = acc[rr][0]*wc4[0] + acc[rr][1]*wc4[1] + acc[rr][2]*wc4[2] + acc[rr][3]*wc4[3];
    #pragma unroll
    for (int m = 1; m < 16; m <<= 1) sd[rr] += __shfl_xor(sd[rr], m, 64);
  }
  if (tx == 0) {
    int j0r = i0 + r0;
    #pragma unroll
    for (int rr = 0; rr < 4; rr++)
      ws[OFF_SP + colblk * NN + j0r + rr] = sd[rr];
  }
}

// ---- kernel 3: finalize s + partial moments. 512 blocks x 16 j each. -------
__global__ __launch_bounds__(256) void k_mom(float* __restrict__ ws) {
  __shared__ float sl[JCH];
  int b = blockIdx.x;
  int tid = threadIdx.x;
  int j0 = b * JCH;
  if (tid < JCH) {
    int j = j0 + tid;
    float s = ws[OFF_SP + j] + ws[OFF_SP + NN + j]
            + ws[OFF_SP + 2 * NN + j] + ws[OFF_SP + 3 * NN + j];
    sl[tid] = s;
    ws[OFF_S + j] = s;                     // k_out consumes this
  }
  __syncthreads();
  float acc[DD];
  #pragma unroll
  for (int p = 0; p < DD; p++) acc[p] = 0.f;
  const float* Rp = ws + OFF_R;
  #pragma unroll
  for (int jj = 0; jj < JCH; jj++) {
    float rv = Rp[(size_t)(j0 + jj) * CC + tid];
    float sj = sl[jj];
    float pw = 1.f;
    #pragma unroll
    for (int p = 0; p < DD; p++) { acc[p] = fmaf(pw, rv, acc[p]); pw *= sj; }
  }
  #pragma unroll
  for (int p = 0; p < DD; p++)
    ws[OFF_PM + ((size_t)b * DD + p) * CC + tid] = acc[p];
  if (tid < DD) {
    float m = 0.f;
    for (int jj = 0; jj < JCH; jj++) {
      float sj = sl[jj], pw = 1.f;
      for (int p = 0; p < tid; p++) pw *= sj;
      m += pw;
    }
    ws[OFF_PMU + b * DD + tid] = m;
  }
}

// --- kernel 4: reduce partials -> M, mu. 257 blocks (R26-proven). -----------
__global__ __launch_bounds__(256) void k_mred(float* __restrict__ ws) {
  __shared__ float red[16][17];
  int tid = threadIdx.x;
  int posL = tid & 15, grp = tid >> 4;
  if (blockIdx.x < 256) {
    int pos = blockIdx.x * 16 + posL;         // (p,c) position in 16x256
    int b0 = grp * 32;
    float s0 = 0.f, s1 = 0.f, s2 = 0.f, s3 = 0.f;
    #pragma unroll
    for (int k = 0; k < 32; k += 4) {
      s0 += ws[OFF_PM + (size_t)(b0 + k + 0) * (DD * CC) + pos];
      s1 += ws[OFF_PM + (size_t)(b0 + k + 1) * (DD * CC) + pos];
      s2 += ws[OFF_PM + (size_t)(b0 + k + 2) * (DD * CC) + pos];
      s3 += ws[OFF_PM + (size_t)(b0 + k + 3) * (DD * CC) + pos];
    }
    red[grp][posL] = (s0 + s1) + (s2 + s3);
    __syncthreads();
    if (grp == 0) {
      float m = 0.f;
      #pragma unroll
      for (int k = 0; k < 16; k++) m += red[k][posL];
      ws[OFF_M + pos] = m;
    }
  } else {
    int b0 = grp * 32;
    float s = 0.f;
    #pragma unroll
    for (int k = 0; k < 32; k++)
      s += ws[OFF_PMU + (b0 + k) * DD + posL];
    red[grp][posL] = s;
    __syncthreads();
    if (grp == 0) {
      float m = 0.f;
      #pragma unroll
      for (int k = 0; k < 16; k++) m += red[k][posL];
      ws[OFF_MU + posL] = m;
    }
  }
}

// ---------------- kernel 5: out = (r+b)*m_i + (Z@r)_i/N via moments ---------
__global__ __launch_bounds__(256) void k_out(const float* __restrict__ br,
                                             const float* __restrict__ ws,
                                             float* __restrict__ out) {
  __shared__ float Ml[DD * CC];            // 16 KB
  __shared__ float dt[256], mul[DD], brl[CC];
  int tid = threadIdx.x;
  #pragma unroll
  for (int q = 0; q < DD; q++) Ml[q * CC + tid] = ws[OFF_M + q * CC + tid];
  dt[tid] = ws[OFF_D + tid];
  brl[tid] = br[tid];
  if (tid < DD) mul[tid] = ws[OFF_MU + tid];
  __syncthreads();
  int idx = blockIdx.x * 256 + tid;        // 1024 blocks; 32 threads per row
  int i = idx >> 5;
  int l32 = idx & 31;
  float a = ws[OFF_S + i] + ws[OFF_C0];
  float apow[DD];
  apow[0] = 1.f;
  #pragma unroll
  for (int p = 1; p < DD; p++) apow[p] = apow[p - 1] * a;
  float Q[DD];
  #pragma unroll
  for (int m = 0; m < DD; m++) {
    float q = 0.f;
    #pragma unroll
    for (int t = 0; t + m < DD; t++)
      q = fmaf(dt[(m + t) * 16 + m], apow[t], q);
    Q[m] = q;
  }
  float mi = 0.f;
  #pragma unroll
  for (int m = 0; m < DD; m++) mi = fmaf(Q[m], mul[m], mi);
  mi *= (1.0f / NN);
  #pragma unroll
  for (int t8 = 0; t8 < 8; t8++) {
    int c = l32 + t8 * 32;
    float v = 0.f;
    #pragma unroll
    for (int m = 0; m < DD; m++) v = fmaf(Q[m], Ml[m * CC + c], v);
    float rv = ws[OFF_R + (size_t)i * CC + c];
    out[(size_t)i * CC + c] = (rv + brl[c]) * mi + v * (1.0f / NN);
  }
}

extern "C" void kernel_launch(void* const* d_in, const int* in_sizes, int n_in,
                              void* d_out, int out_size, void* d_ws, size_t ws_size,
                              hipStream_t stream) {
  const float* x  = (const float*)d_in[0];
  const float* w  = (const float*)d_in[1];
  const float* br = (const float*)d_in[2];
  const float* wc = (const float*)d_in[3];
  const float* bc = (const float*)d_in[4];
  float* ws = (float*)d_ws;
  float* out = (float*)d_out;
  (void)in_sizes; (void)n_in; (void)out_size; (void)ws_size;

  k_fit<<<1, 256, 0, stream>>>(br, wc, bc, ws);
  k_r<<<512, 256, 0, stream>>>(x, w, wc, ws);
  k_mom<<<512, 256, 0, stream>>>(ws);
  k_mred<<<257, 256, 0, stream>>>(ws);
  k_out<<<1024, 256, 0, stream>>>(br, ws, out);
}

// Round 30
// 74.909 us; speedup vs baseline: 2.5234x; 1.2320x over previous
//
#include <hip/hip_runtime.h>
#include <hip/hip_bf16.h>
#include <stdint.h>

#define NN 8192
#define CC 256
#define DD 16                              // poly terms (degree 15)
#define NCH 512                            // moment j-chunks
#define JCH 16                             // j per chunk
#define FITHALF 5.0                        // Chebyshev fit on [-5,5]; |s_i+s_j+c0|<=~3.2

typedef float f32x4 __attribute__((ext_vector_type(4)));
typedef float f32x2 __attribute__((ext_vector_type(2)));

// ---- workspace layout (float offsets). Total ~17.2 MB. ----
#define OFF_WT  0                          // 256*256 transposed w_reduce
#define OFF_R   (OFF_WT + CC*CC)           // N*C fp32 r
#define OFF_S   (OFF_R + NN*CC)            // N fp32 s
#define OFF_C0  (OFF_S + NN)               // [0]=c0
#define OFF_SP  (OFF_C0 + 16)              // 4*N fp32 s partials (per colblk)
#define OFF_D   (OFF_SP + 4*NN)            // 16x16 d[k][m] = c_k * C(k,m)
#define OFF_MU  (OFF_D + 256)              // 16 mu_p = sum_j s_j^p
#define OFF_M   (OFF_MU + 16)              // 16x256 M_p[c] = sum_j s_j^p r_j[c]
#define OFF_PM  (OFF_M + DD*CC)            // NCH x 16x256 partial M (8.4 MB)
#define OFF_PMU (OFF_PM + NCH*DD*CC)       // NCH x 16 partial mu

// -- kernel 1: 65 blocks. 0-63: tiled transpose Wr (+c0 in blk 0); 64: fit. --
__global__ __launch_bounds__(256) void k_prep(const float* __restrict__ w,
                                              const float* __restrict__ br,
                                              const float* __restrict__ wcv,
                                              const float* __restrict__ bc,
                                              float* __restrict__ ws) {
  __shared__ float t[32][33];
  __shared__ double fd[32], cnod[32], ac[16], alpha[16][16], cmon[16];
  int bi = blockIdx.x;
  if (bi < 64) {                           // ---- transpose path ----
    int tr = bi >> 3, tc = bi & 7;
    int tx = threadIdx.x & 31, ty = threadIdx.x >> 5;
    #pragma unroll
    for (int p = 0; p < 4; p++) {
      int row = ty + p * 8;
      t[row][tx] = w[(tr * 32 + row) * CC + tc * 32 + tx];
    }
    __syncthreads();
    #pragma unroll
    for (int p = 0; p < 4; p++) {
      int row = ty + p * 8;
      ws[OFF_WT + (tc * 32 + row) * CC + tr * 32 + tx] = t[tx][row];
    }
    if (bi == 0 && threadIdx.x < 64) {
      int lane = threadIdx.x;
      f32x4 b4 = *(const f32x4*)&br[lane * 4];
      f32x4 w4 = *(const f32x4*)&wcv[lane * 4];
      float d = b4[0]*w4[0] + b4[1]*w4[1] + b4[2]*w4[2] + b4[3]*w4[3];
      #pragma unroll
      for (int m = 32; m >= 1; m >>= 1) d += __shfl_xor(d, m, 64);
      if (lane == 0) ws[OFF_C0] = d + bc[0];
    }
  } else {                                 // ---- Chebyshev fit path ----
    int tt = threadIdx.x;
    if (tt < 32) {
      double th = (3.14159265358979323846 * (tt + 0.5)) / 32.0;
      double c = cos(th);
      cnod[tt] = c;
      fd[tt] = 1.0 / (1.0 + exp(-FITHALF * c));
    }
    __syncthreads();
    if (tt < 16) {                         // DCT -> Chebyshev coeffs
      double sum = 0.0;
      for (int n = 0; n < 32; n++) {
        double t0 = 1.0, t1 = cnod[n], tk = t1;
        for (int k = 2; k <= tt; k++) { tk = 2.0 * cnod[n] * t1 - t0; t0 = t1; t1 = tk; }
        if (tt == 0) tk = 1.0;
        sum += fd[n] * tk;
      }
      ac[tt] = ((tt == 0) ? 1.0 : 2.0) / 32.0 * sum;
    }
    __syncthreads();
    if (tt == 0) {                         // Cheb->monomial basis (in u=y/H)
      for (int k = 0; k < 16; k++) for (int m = 0; m < 16; m++) alpha[k][m] = 0.0;
      alpha[0][0] = 1.0; alpha[1][1] = 1.0;
      for (int k = 2; k < 16; k++)
        for (int m = 0; m < 16; m++) {
          double v = -alpha[k-2][m];
          if (m > 0) v += 2.0 * alpha[k-1][m-1];
          alpha[k][m] = v;
        }
    }
    __syncthreads();
    if (tt < 16) {                         // cmon[m], parallel over m
      double pm = 0.0;
      for (int k = 0; k < 16; k++) pm += ac[k] * alpha[k][tt];
      double p5 = 1.0;
      for (int i = 0; i < tt; i++) p5 *= FITHALF;
      cmon[tt] = pm / p5;
    }
    __syncthreads();
    if (tt == 0) {                         // Pascal binomials
      for (int k = 0; k < 16; k++) for (int m = 0; m < 16; m++) alpha[k][m] = 0.0;
      alpha[0][0] = 1.0;
      for (int k = 1; k < 16; k++)
        for (int m = 0; m <= k; m++)
          alpha[k][m] = ((m > 0) ? alpha[k-1][m-1] : 0.0) + ((m < k) ? alpha[k-1][m] : 0.0);
    }
    __syncthreads();
    {                                      // d[k][m] = c_k * C(k,m), 256 threads
      int k = tt >> 4, m = tt & 15;
      ws[OFF_D + tt] = (float)((m <= k) ? cmon[k] * alpha[k][m] : 0.0);
    }
  }
}

// ------- kernel 2: r = x @ Wr^T (fp32) + s partials (proven R21 core) -------
__global__ __launch_bounds__(256) void k_r(const float* __restrict__ x,
                                           const float* __restrict__ wcv,
                                           float* __restrict__ ws) {
  __shared__ float xs[64][260];
  int bi = blockIdx.x;
  int rowblk = bi >> 2, colblk = bi & 3;
  int tid = threadIdx.x;
  int i0 = rowblk * 64;
  for (int t = tid; t < 64 * 64; t += 256) {
    int rr = t >> 6, c4 = t & 63;
    *(f32x4*)&xs[rr][c4 * 4] = *(const f32x4*)&x[(i0 + rr) * CC + c4 * 4];
  }
  __syncthreads();
  int tx = tid & 15, ty = tid >> 4;
  int cbase = colblk * 64 + tx * 4;
  int r0 = ty * 4;
  float acc[4][4] = {};
  const float* wt = ws + OFF_WT;
  for (int k = 0; k < CC; k += 2) {
    f32x4 wv0 = *(const f32x4*)&wt[k * CC + cbase];
    f32x4 wv1 = *(const f32x4*)&wt[(k + 1) * CC + cbase];
    f32x2 xv[4];
    #pragma unroll
    for (int rr = 0; rr < 4; rr++) xv[rr] = *(const f32x2*)&xs[r0 + rr][k];
    #pragma unroll
    for (int rr = 0; rr < 4; rr++)
      #pragma unroll
      for (int cc = 0; cc < 4; cc++)
        acc[rr][cc] = fmaf(xv[rr][1], wv1[cc], fmaf(xv[rr][0], wv0[cc], acc[rr][cc]));
  }
  #pragma unroll
  for (int rr = 0; rr < 4; rr++) {
    f32x4 o = {acc[rr][0], acc[rr][1], acc[rr][2], acc[rr][3]};
    *(f32x4*)&ws[OFF_R + (size_t)(i0 + r0 + rr) * CC + cbase] = o;
  }
  // s partials: this block's 64-col contribution, shuffle-reduced over tx
  f32x4 wc4 = *(const f32x4*)&wcv[cbase];
  float sd[4];
  #pragma unroll
  for (int rr = 0; rr < 4; rr++) {
    sd[rr] = acc[rr][0]*wc4[0] + acc[rr][1]*wc4[1] + acc[rr][2]*wc4[2] + acc[rr][3]*wc4[3];
    #pragma unroll
    for (int m = 1; m < 16; m <<= 1) sd[rr] += __shfl_xor(sd[rr], m, 64);
  }
  if (tx == 0) {
    int j0r = i0 + r0;
    #pragma unroll
    for (int rr = 0; rr < 4; rr++)
      ws[OFF_SP + colblk * NN + j0r + rr] = sd[rr];
  }
}

// ---- kernel 3: finalize s + partial moments. 512 blocks x 16 j each. -------
__global__ __launch_bounds__(256) void k_mom(float* __restrict__ ws) {
  __shared__ float sl[JCH];
  int b = blockIdx.x;
  int tid = threadIdx.x;
  int j0 = b * JCH;
  if (tid < JCH) {
    int j = j0 + tid;
    float s = ws[OFF_SP + j] + ws[OFF_SP + NN + j]
            + ws[OFF_SP + 2 * NN + j] + ws[OFF_SP + 3 * NN + j];
    sl[tid] = s;
    ws[OFF_S + j] = s;                     // k_out consumes this
  }
  __syncthreads();
  float acc[DD];
  #pragma unroll
  for (int p = 0; p < DD; p++) acc[p] = 0.f;
  const float* Rp = ws + OFF_R;
  #pragma unroll
  for (int jj = 0; jj < JCH; jj++) {
    float rv = Rp[(size_t)(j0 + jj) * CC + tid];
    float sj = sl[jj];
    float pw = 1.f;
    #pragma unroll
    for (int p = 0; p < DD; p++) { acc[p] = fmaf(pw, rv, acc[p]); pw *= sj; }
  }
  #pragma unroll
  for (int p = 0; p < DD; p++)
    ws[OFF_PM + ((size_t)b * DD + p) * CC + tid] = acc[p];
  if (tid < DD) {
    float m = 0.f;
    for (int jj = 0; jj < JCH; jj++) {
      float sj = sl[jj], pw = 1.f;
      for (int p = 0; p < tid; p++) pw *= sj;
      m += pw;
    }
    ws[OFF_PMU + b * DD + tid] = m;
  }
}

// --- kernel 4: reduce partials -> M, mu. 257 blocks, high-MLP coalesced. ----
__global__ __launch_bounds__(256) void k_mred(float* __restrict__ ws) {
  __shared__ float red[16][17];
  int tid = threadIdx.x;
  int posL = tid & 15, grp = tid >> 4;
  if (blockIdx.x < 256) {
    int pos = blockIdx.x * 16 + posL;         // (p,c) position in 16x256
    int b0 = grp * 32;
    float s0 = 0.f, s1 = 0.f, s2 = 0.f, s3 = 0.f;
    #pragma unroll
    for (int k = 0; k < 32; k += 4) {
      s0 += ws[OFF_PM + (size_t)(b0 + k + 0) * (DD * CC) + pos];
      s1 += ws[OFF_PM + (size_t)(b0 + k + 1) * (DD * CC) + pos];
      s2 += ws[OFF_PM + (size_t)(b0 + k + 2) * (DD * CC) + pos];
      s3 += ws[OFF_PM + (size_t)(b0 + k + 3) * (DD * CC) + pos];
    }
    red[grp][posL] = (s0 + s1) + (s2 + s3);
    __syncthreads();
    if (grp == 0) {
      float m = 0.f;
      #pragma unroll
      for (int k = 0; k < 16; k++) m += red[k][posL];
      ws[OFF_M + pos] = m;
    }
  } else {
    int b0 = grp * 32;
    float s = 0.f;
    #pragma unroll
    for (int k = 0; k < 32; k++)
      s += ws[OFF_PMU + (b0 + k) * DD + posL];
    red[grp][posL] = s;
    __syncthreads();
    if (grp == 0) {
      float m = 0.f;
      #pragma unroll
      for (int k = 0; k < 16; k++) m += red[k][posL];
      ws[OFF_MU + posL] = m;
    }
  }
}

// ---------------- kernel 5: out = (r+b)*m_i + (Z@r)_i/N via moments ---------
__global__ __launch_bounds__(256) void k_out(const float* __restrict__ br,
                                             const float* __restrict__ ws,
                                             float* __restrict__ out) {
  __shared__ float Ml[DD * CC];            // 16 KB
  __shared__ float dt[256], mul[DD], brl[CC];
  int tid = threadIdx.x;
  #pragma unroll
  for (int q = 0; q < DD; q++) Ml[q * CC + tid] = ws[OFF_M + q * CC + tid];
  dt[tid] = ws[OFF_D + tid];
  brl[tid] = br[tid];
  if (tid < DD) mul[tid] = ws[OFF_MU + tid];
  __syncthreads();
  int idx = blockIdx.x * 256 + tid;        // 1024 blocks; 32 threads per row
  int i = idx >> 5;
  int l32 = idx & 31;
  float a = ws[OFF_S + i] + ws[OFF_C0];
  float apow[DD];
  apow[0] = 1.f;
  #pragma unroll
  for (int p = 1; p < DD; p++) apow[p] = apow[p - 1] * a;
  float Q[DD];
  #pragma unroll
  for (int m = 0; m < DD; m++) {
    float q = 0.f;
    #pragma unroll
    for (int t = 0; t + m < DD; t++)
      q = fmaf(dt[(m + t) * 16 + m], apow[t], q);
    Q[m] = q;
  }
  float mi = 0.f;
  #pragma unroll
  for (int m = 0; m < DD; m++) mi = fmaf(Q[m], mul[m], mi);
  mi *= (1.0f / NN);
  #pragma unroll
  for (int t8 = 0; t8 < 8; t8++) {
    int c = l32 + t8 * 32;
    float v = 0.f;
    #pragma unroll
    for (int m = 0; m < DD; m++) v = fmaf(Q[m], Ml[m * CC + c], v);
    float rv = ws[OFF_R + (size_t)i * CC + c];
    out[(size_t)i * CC + c] = (rv + brl[c]) * mi + v * (1.0f / NN);
  }
}

extern "C" void kernel_launch(void* const* d_in, const int* in_sizes, int n_in,
                              void* d_out, int out_size, void* d_ws, size_t ws_size,
                              hipStream_t stream) {
  const float* x  = (const float*)d_in[0];
  const float* w  = (const float*)d_in[1];
  const float* br = (const float*)d_in[2];
  const float* wc = (const float*)d_in[3];
  const float* bc = (const float*)d_in[4];
  float* ws = (float*)d_ws;
  float* out = (float*)d_out;
  (void)in_sizes; (void)n_in; (void)out_size; (void)ws_size;

  k_prep<<<65, 256, 0, stream>>>(w, br, wc, bc, ws);
  k_r<<<512, 256, 0, stream>>>(x, wc, ws);
  k_mom<<<512, 256, 0, stream>>>(ws);
  k_mred<<<257, 256, 0, stream>>>(ws);
  k_out<<<1024, 256, 0, stream>>>(br, ws, out);
}